// Round 2
// baseline (515.720 us; speedup 1.0000x reference)
//
#include <hip/hip_runtime.h>
#include <math.h>

#define N_PTS (128*128*128)          // 2,097,152
#define T_HASH 4194304
#define T_MASK (T_HASH - 1)
#define ENTRY_STRIDE 16              // floats per transposed entry (64 B aligned)

#define PA_BLOCKS  2048
#define PA_THREADS 256
#define PA_STRIDE  (PA_BLOCKS * PA_THREADS)   // 524288
#define PA_ITERS   (N_PTS / PA_STRIDE)        // 4 (exact)

__device__ __forceinline__ unsigned hash_idx(int x, int y, int z) {
    return ((unsigned)x ^ ((unsigned)y * 2654435761u)
                        ^ ((unsigned)z * 805459861u)) & T_MASK;
}

// ---------------------------------------------------------------------------
// Kernel 1: transpose (14, T_HASH) -> (T_HASH, 16) padded.
// 256 entries/block, LDS 16.5 KB -> 8 blocks/CU (100% occupancy).
// Reads: float2 x7/thread (512B/wave/instr, coalesced).
// Stores: float4 x4/thread (1KB/wave/instr, contiguous).
// LDS [16][258]: write side contiguous (conflict-free), read side 2-way (free).
// ---------------------------------------------------------------------------
__global__ __launch_bounds__(256)
void transpose_kernel(const float* __restrict__ table, float* __restrict__ tt) {
    __shared__ float sh[16][258];
    const int t  = threadIdx.x;
    const int i0 = blockIdx.x * 256;

    #pragma unroll
    for (int k = 0; k < 7; ++k) {
        const int l    = t + k * 256;        // [0, 1792)
        const int row  = l >> 7;             // 0..13
        const int col2 = (l & 127) * 2;      // float col, x2
        const float2 v = *(const float2*)(table + (size_t)row * T_HASH + i0 + col2);
        *(float2*)&sh[row][col2] = v;
    }
    __syncthreads();

    const int c  = t & 3;                // which float4 of the entry
    const int r0 = c * 4;                // first source row
    const int p0 = t >> 2;               // entry within block (0..63)
    float4* dst = (float4*)(tt + (size_t)i0 * ENTRY_STRIDE);
    #pragma unroll
    for (int k = 0; k < 4; ++k) {
        const int p = p0 + k * 64;
        float vx = sh[r0 + 0][p];
        float vy = sh[r0 + 1][p];
        float vz = sh[r0 + 2][p];
        float vw = sh[r0 + 3][p];
        if (c == 3) { vz = 0.f; vw = 0.f; }          // pad floats 14,15
        dst[(size_t)p * 4 + c] = make_float4(vx, vy, vz, vw);  // contiguous 1KB/wave
    }
}

// ---------------------------------------------------------------------------
// Pass A: single gather does EVERYTHING except the means affine.
//  - writes cov / harmonics / opacity (final, NONTEMPORAL -> keep L3 for tt)
//  - writes raw dm = g[0:3] into the means slot (regular; re-read by pass B)
//  - accumulates sum / sumsq -> 2 double atomics per block
// ---------------------------------------------------------------------------
__global__ __launch_bounds__(256)
void fused_main_kernel(const int*   __restrict__ coords,
                       const float* __restrict__ tt,
                       const float* __restrict__ far_p,
                       const int*   __restrict__ vs_p,
                       float*       __restrict__ out,
                       double*      __restrict__ acc) {
    const int base = blockIdx.x * PA_THREADS + threadIdx.x;

    int cx[PA_ITERS], cy[PA_ITERS], cz[PA_ITERS];
    #pragma unroll
    for (int it = 0; it < PA_ITERS; ++it) {
        const size_t b = (size_t)(base + it * PA_STRIDE) * 3;
        cx[it] = coords[b + 0];
        cy[it] = coords[b + 1];
        cz[it] = coords[b + 2];
    }

    float4 f0[PA_ITERS], f1[PA_ITERS], f2[PA_ITERS], f3[PA_ITERS];
    #pragma unroll
    for (int it = 0; it < PA_ITERS; ++it) {
        const unsigned idx = hash_idx(cx[it], cy[it], cz[it]);
        const float4* e = (const float4*)(tt + (size_t)idx * ENTRY_STRIDE);
        f0[it] = e[0]; f1[it] = e[1]; f2[it] = e[2]; f3[it] = e[3];
    }

    const float far_s = far_p[0];
    const float vs    = (float)vs_p[0];
    const float tfv   = 2.f * far_s / vs;

    float s = 0.f, ss = 0.f;
    #pragma unroll
    for (int it = 0; it < PA_ITERS; ++it) {
        const int i = base + it * PA_STRIDE;

        // raw dm -> means slot (finalized in pass B); accumulate stats
        const float g0 = f0[it].x, g1 = f0[it].y, g2 = f0[it].z;
        out[(size_t)i * 3 + 0] = g0;
        out[(size_t)i * 3 + 1] = g1;
        out[(size_t)i * 3 + 2] = g2;
        s  += g0 + g1 + g2;
        ss += g0 * g0 + g1 * g1 + g2 * g2;

        // quaternion -> R
        float qr = f0[it].w, qx = f1[it].x, qy = f1[it].y, qz = f1[it].z;
        const float qinv = 1.f / sqrtf(qr * qr + qx * qx + qy * qy + qz * qz);
        qr *= qinv; qx *= qinv; qy *= qinv; qz *= qinv;

        float R[3][3];
        R[0][0] = 1.f - 2.f * (qy * qy + qz * qz);
        R[0][1] = 2.f * (qx * qy - qr * qz);
        R[0][2] = 2.f * (qx * qz + qr * qy);
        R[1][0] = 2.f * (qx * qy + qr * qz);
        R[1][1] = 1.f - 2.f * (qx * qx + qz * qz);
        R[1][2] = 2.f * (qy * qz - qr * qx);
        R[2][0] = 2.f * (qx * qz - qr * qy);
        R[2][1] = 2.f * (qy * qz + qr * qx);
        R[2][2] = 1.f - 2.f * (qx * qx + qy * qy);

        float sc[3];
        sc[0] = tfv / (1.f + expf(-f1[it].w));
        sc[1] = tfv / (1.f + expf(-f2[it].x));
        sc[2] = tfv / (1.f + expf(-f2[it].y));

        float L[3][3];
        #pragma unroll
        for (int r = 0; r < 3; ++r)
            #pragma unroll
            for (int j = 0; j < 3; ++j)
                L[r][j] = R[r][j] * sc[j];

        float* covp = out + (size_t)3 * N_PTS + (size_t)i * 9;
        #pragma unroll
        for (int r = 0; r < 3; ++r)
            #pragma unroll
            for (int col = 0; col < 3; ++col) {
                const float a = L[r][0] * L[col][0]
                              + L[r][1] * L[col][1]
                              + L[r][2] * L[col][2];
                __builtin_nontemporal_store(a, covp + r * 3 + col);
            }

        float* harp = out + (size_t)12 * N_PTS + (size_t)i * 3;
        __builtin_nontemporal_store(f2[it].z, harp + 0);
        __builtin_nontemporal_store(f2[it].w, harp + 1);
        __builtin_nontemporal_store(f3[it].x, harp + 2);

        const float op = 1.f / (1.f + expf(-(f3[it].y - 4.f)));
        __builtin_nontemporal_store(op, out + (size_t)15 * N_PTS + i);
    }

    // block reduction -> 2 double atomics
    #pragma unroll
    for (int off = 32; off > 0; off >>= 1) {
        s  += __shfl_down(s, off, 64);
        ss += __shfl_down(ss, off, 64);
    }
    __shared__ float sh_s[4], sh_ss[4];
    const int lane = threadIdx.x & 63;
    const int wid  = threadIdx.x >> 6;
    if (lane == 0) { sh_s[wid] = s; sh_ss[wid] = ss; }
    __syncthreads();
    if (threadIdx.x == 0) {
        float ts = 0.f, tss = 0.f;
        for (int w = 0; w < 4; ++w) { ts += sh_s[w]; tss += sh_ss[w]; }
        atomicAdd(&acc[0], (double)ts);
        atomicAdd(&acc[1], (double)tss);
    }
}

// ---------------------------------------------------------------------------
// Pass B: streaming finalize of means (~75 MB total traffic).
// means = (dm_raw - mean) * inv_std * dm_scale + voxel_center
// ---------------------------------------------------------------------------
__global__ __launch_bounds__(256)
void finalize_means_kernel(const int*    __restrict__ coords,
                           const float*  __restrict__ cam,
                           const float*  __restrict__ far_p,
                           const int*    __restrict__ vs_p,
                           const double* __restrict__ acc,
                           float*        __restrict__ out) {
    const double n      = 3.0 * (double)N_PTS;
    const double sum    = acc[0];
    const double sumsq  = acc[1];
    const float  mean   = (float)(sum / n);
    const float  inv_std= (float)(1.0 / sqrt((sumsq - sum * sum / n) / (n - 1.0)));

    const float far_s = far_p[0];
    const float vs    = (float)vs_p[0];
    const float a     = inv_std * (2.f * far_s / vs / 6.f);
    const float off_c = -far_s + far_s / vs;
    const float cam_t[3] = { cam[0], cam[1], cam[2] };

    const int base = blockIdx.x * PA_THREADS + threadIdx.x;
    #pragma unroll
    for (int it = 0; it < PA_ITERS; ++it) {
        const int i = base + it * PA_STRIDE;
        const size_t b = (size_t)i * 3;
        const int cc[3] = { coords[b + 0], coords[b + 1], coords[b + 2] };
        #pragma unroll
        for (int k = 0; k < 3; ++k) {
            const float vc = (float)cc[k] / vs * 2.f * far_s + off_c + cam_t[k];
            const float dm = out[b + k];
            __builtin_nontemporal_store((dm - mean) * a + vc, out + b + k);
        }
    }
}

// ---------------------------------------------------------------------------
// Fallback path (workspace too small for the transposed table).
// ---------------------------------------------------------------------------
__global__ void reduce_kernel_o(const int* __restrict__ coords,
                                const float* __restrict__ table,
                                double* __restrict__ acc) {
    float s = 0.f, ss = 0.f;
    const int stride = gridDim.x * blockDim.x;
    for (int i = blockIdx.x * blockDim.x + threadIdx.x; i < N_PTS; i += stride) {
        const unsigned idx = hash_idx(coords[i*3], coords[i*3+1], coords[i*3+2]);
        float g0 = table[idx];
        float g1 = table[T_HASH + idx];
        float g2 = table[2 * T_HASH + idx];
        s  += g0 + g1 + g2;
        ss += g0 * g0 + g1 * g1 + g2 * g2;
    }
    #pragma unroll
    for (int off = 32; off > 0; off >>= 1) {
        s  += __shfl_down(s, off, 64);
        ss += __shfl_down(ss, off, 64);
    }
    __shared__ float sh_s[4], sh_ss[4];
    const int lane = threadIdx.x & 63;
    const int wid  = threadIdx.x >> 6;
    if (lane == 0) { sh_s[wid] = s; sh_ss[wid] = ss; }
    __syncthreads();
    if (threadIdx.x == 0) {
        float ts = 0.f, tss = 0.f;
        for (int w = 0; w < 4; ++w) { ts += sh_s[w]; tss += sh_ss[w]; }
        atomicAdd(&acc[0], (double)ts);
        atomicAdd(&acc[1], (double)tss);
    }
}

__global__ void main_kernel_o(const int* __restrict__ coords,
                              const float* __restrict__ tab,
                              const float* __restrict__ cam,
                              const float* __restrict__ far_p,
                              const int* __restrict__ vs_p,
                              const double* __restrict__ acc,
                              float* __restrict__ out) {
    const int i = blockIdx.x * blockDim.x + threadIdx.x;
    if (i >= N_PTS) return;

    const float far_s = far_p[0];
    const float vs    = (float)vs_p[0];

    const double n      = 3.0 * (double)N_PTS;
    const double sum    = acc[0];
    const double sumsq  = acc[1];
    const float mean    = (float)(sum / n);
    const float inv_std = (float)(1.0 / sqrt((sumsq - sum * sum / n) / (n - 1.0)));

    const int cx = coords[i * 3 + 0];
    const int cy = coords[i * 3 + 1];
    const int cz = coords[i * 3 + 2];
    const unsigned idx = hash_idx(cx, cy, cz);

    float g[14];
    #pragma unroll
    for (int j = 0; j < 14; ++j)
        g[j] = tab[(size_t)j * T_HASH + idx];

    const float two_far_over_vs = 2.f * far_s / vs;
    const float dm_scale = two_far_over_vs / 6.f;
    const float c_f[3] = { (float)cx, (float)cy, (float)cz };
    #pragma unroll
    for (int k = 0; k < 3; ++k) {
        const float vc = c_f[k] / vs * 2.f * far_s - far_s + cam[k] + far_s / vs;
        out[(size_t)i * 3 + k] = (g[k] - mean) * inv_std * dm_scale + vc;
    }

    float qr = g[3], qx = g[4], qy = g[5], qz = g[6];
    const float qinv = 1.f / sqrtf(qr * qr + qx * qx + qy * qy + qz * qz);
    qr *= qinv; qx *= qinv; qy *= qinv; qz *= qinv;

    float R[3][3];
    R[0][0] = 1.f - 2.f * (qy * qy + qz * qz);
    R[0][1] = 2.f * (qx * qy - qr * qz);
    R[0][2] = 2.f * (qx * qz + qr * qy);
    R[1][0] = 2.f * (qx * qy + qr * qz);
    R[1][1] = 1.f - 2.f * (qx * qx + qz * qz);
    R[1][2] = 2.f * (qy * qz - qr * qx);
    R[2][0] = 2.f * (qx * qz - qr * qy);
    R[2][1] = 2.f * (qy * qz + qr * qx);
    R[2][2] = 1.f - 2.f * (qx * qx + qy * qy);

    float sc[3];
    #pragma unroll
    for (int k = 0; k < 3; ++k)
        sc[k] = two_far_over_vs / (1.f + expf(-g[7 + k]));

    float* covp = out + (size_t)3 * N_PTS + (size_t)i * 9;
    #pragma unroll
    for (int r = 0; r < 3; ++r) {
        #pragma unroll
        for (int c = 0; c < 3; ++c) {
            float a = 0.f;
            #pragma unroll
            for (int j = 0; j < 3; ++j)
                a += (R[r][j] * sc[j]) * (R[c][j] * sc[j]);
            covp[r * 3 + c] = a;
        }
    }

    float* harp = out + (size_t)12 * N_PTS + (size_t)i * 3;
    #pragma unroll
    for (int k = 0; k < 3; ++k)
        harp[k] = g[10 + k];

    out[(size_t)15 * N_PTS + i] = 1.f / (1.f + expf(-(g[13] - 4.f)));
}

extern "C" void kernel_launch(void* const* d_in, const int* in_sizes, int n_in,
                              void* d_out, int out_size, void* d_ws, size_t ws_size,
                              hipStream_t stream) {
    const int*   coords = (const int*)d_in[0];
    const float* table  = (const float*)d_in[1];
    const float* cam    = (const float*)d_in[2];
    const float* far_p  = (const float*)d_in[3];
    const int*   vs_p   = (const int*)d_in[4];
    float*       out    = (float*)d_out;

    double* acc = (double*)d_ws;
    float*  tt  = (float*)((char*)d_ws + 256);

    const size_t need = 256 + (size_t)T_HASH * ENTRY_STRIDE * sizeof(float);

    hipMemsetAsync(d_ws, 0, 2 * sizeof(double), stream);

    if (ws_size >= need) {
        transpose_kernel<<<T_HASH / 256, 256, 0, stream>>>(table, tt);
        fused_main_kernel<<<PA_BLOCKS, PA_THREADS, 0, stream>>>(coords, tt, far_p,
                                                                vs_p, out, acc);
        finalize_means_kernel<<<PA_BLOCKS, PA_THREADS, 0, stream>>>(coords, cam,
                                                                    far_p, vs_p,
                                                                    acc, out);
    } else {
        const int threads = 256;
        const int blocks  = (N_PTS + threads - 1) / threads;
        reduce_kernel_o<<<2048, 256, 0, stream>>>(coords, table, acc);
        main_kernel_o<<<blocks, threads, 0, stream>>>(coords, table, cam,
                                                      far_p, vs_p, acc, out);
    }
}

// Round 3
// 499.944 us; speedup vs baseline: 1.0316x; 1.0316x over previous
//
#include <hip/hip_runtime.h>
#include <math.h>

#define N_PTS (128*128*128)          // 2,097,152
#define T_HASH 4194304
#define T_MASK (T_HASH - 1)
#define ENTRY_STRIDE 16              // floats per transposed entry (64 B aligned)

#define PA_BLOCKS  2048
#define PA_THREADS 256
#define PA_STRIDE  (PA_BLOCKS * PA_THREADS)   // 524288
#define PA_ITERS   (N_PTS / PA_STRIDE)        // 4 (exact)

__device__ __forceinline__ unsigned hash_idx(int x, int y, int z) {
    return ((unsigned)x ^ ((unsigned)y * 2654435761u)
                        ^ ((unsigned)z * 805459861u)) & T_MASK;
}

// ---------------------------------------------------------------------------
// Kernel 1: transpose (14, T_HASH) -> (T_HASH, 16) padded.
// 256 entries/block, LDS 16.5 KB -> 8 blocks/CU (100% occupancy).
// Reads: float2 x7/thread (512B/wave/instr, coalesced).
// Stores: float4 x4/thread (1KB/wave/instr, contiguous, full 64B entries).
// Also zeroes the accumulator (block 0) so no separate memset dispatch.
// ---------------------------------------------------------------------------
__global__ __launch_bounds__(256)
void transpose_kernel(const float* __restrict__ table, float* __restrict__ tt,
                      double* __restrict__ acc) {
    if (blockIdx.x == 0 && threadIdx.x < 2) acc[threadIdx.x] = 0.0;

    __shared__ float sh[16][258];
    const int t  = threadIdx.x;
    const int i0 = blockIdx.x * 256;

    #pragma unroll
    for (int k = 0; k < 7; ++k) {
        const int l    = t + k * 256;        // [0, 1792)
        const int row  = l >> 7;             // 0..13
        const int col2 = (l & 127) * 2;      // float col, x2
        const float2 v = *(const float2*)(table + (size_t)row * T_HASH + i0 + col2);
        *(float2*)&sh[row][col2] = v;
    }
    __syncthreads();

    const int c  = t & 3;                // which float4 of the entry
    const int r0 = c * 4;                // first source row
    const int p0 = t >> 2;               // entry within block (0..63)
    float4* dst = (float4*)(tt + (size_t)i0 * ENTRY_STRIDE);
    #pragma unroll
    for (int k = 0; k < 4; ++k) {
        const int p = p0 + k * 64;
        float vx = sh[r0 + 0][p];
        float vy = sh[r0 + 1][p];
        float vz = sh[r0 + 2][p];
        float vw = sh[r0 + 3][p];
        if (c == 3) { vz = 0.f; vw = 0.f; }          // pad floats 14,15
        dst[(size_t)p * 4 + c] = make_float4(vx, vy, vz, vw);  // contiguous 1KB/wave
    }
}

// ---------------------------------------------------------------------------
// Pass A: single gather does EVERYTHING except the means affine.
//  - writes cov / harmonics / opacity (final)
//  - writes raw dm = g[0:3] into the means slot (re-read by pass B)
//  - accumulates sum / sumsq -> 2 double atomics per block
// Normal stores throughout (nontemporal hints caused partial-line HBM writes).
// ---------------------------------------------------------------------------
__global__ __launch_bounds__(256)
void fused_main_kernel(const int*   __restrict__ coords,
                       const float* __restrict__ tt,
                       const float* __restrict__ far_p,
                       const int*   __restrict__ vs_p,
                       float*       __restrict__ out,
                       double*      __restrict__ acc) {
    const int base = blockIdx.x * PA_THREADS + threadIdx.x;

    int cx[PA_ITERS], cy[PA_ITERS], cz[PA_ITERS];
    #pragma unroll
    for (int it = 0; it < PA_ITERS; ++it) {
        const size_t b = (size_t)(base + it * PA_STRIDE) * 3;
        cx[it] = coords[b + 0];
        cy[it] = coords[b + 1];
        cz[it] = coords[b + 2];
    }

    float4 f0[PA_ITERS], f1[PA_ITERS], f2[PA_ITERS], f3[PA_ITERS];
    #pragma unroll
    for (int it = 0; it < PA_ITERS; ++it) {
        const unsigned idx = hash_idx(cx[it], cy[it], cz[it]);
        const float4* e = (const float4*)(tt + (size_t)idx * ENTRY_STRIDE);
        f0[it] = e[0]; f1[it] = e[1]; f2[it] = e[2]; f3[it] = e[3];
    }

    const float far_s = far_p[0];
    const float vs    = (float)vs_p[0];
    const float tfv   = 2.f * far_s / vs;

    float s = 0.f, ss = 0.f;
    #pragma unroll
    for (int it = 0; it < PA_ITERS; ++it) {
        const int i = base + it * PA_STRIDE;

        // raw dm -> means slot (finalized in pass B); accumulate stats
        const float g0 = f0[it].x, g1 = f0[it].y, g2 = f0[it].z;
        out[(size_t)i * 3 + 0] = g0;
        out[(size_t)i * 3 + 1] = g1;
        out[(size_t)i * 3 + 2] = g2;
        s  += g0 + g1 + g2;
        ss += g0 * g0 + g1 * g1 + g2 * g2;

        // quaternion -> R
        float qr = f0[it].w, qx = f1[it].x, qy = f1[it].y, qz = f1[it].z;
        const float qinv = 1.f / sqrtf(qr * qr + qx * qx + qy * qy + qz * qz);
        qr *= qinv; qx *= qinv; qy *= qinv; qz *= qinv;

        float R[3][3];
        R[0][0] = 1.f - 2.f * (qy * qy + qz * qz);
        R[0][1] = 2.f * (qx * qy - qr * qz);
        R[0][2] = 2.f * (qx * qz + qr * qy);
        R[1][0] = 2.f * (qx * qy + qr * qz);
        R[1][1] = 1.f - 2.f * (qx * qx + qz * qz);
        R[1][2] = 2.f * (qy * qz - qr * qx);
        R[2][0] = 2.f * (qx * qz - qr * qy);
        R[2][1] = 2.f * (qy * qz + qr * qx);
        R[2][2] = 1.f - 2.f * (qx * qx + qy * qy);

        float sc[3];
        sc[0] = tfv / (1.f + expf(-f1[it].w));
        sc[1] = tfv / (1.f + expf(-f2[it].x));
        sc[2] = tfv / (1.f + expf(-f2[it].y));

        float L[3][3];
        #pragma unroll
        for (int r = 0; r < 3; ++r)
            #pragma unroll
            for (int j = 0; j < 3; ++j)
                L[r][j] = R[r][j] * sc[j];

        float* covp = out + (size_t)3 * N_PTS + (size_t)i * 9;
        #pragma unroll
        for (int r = 0; r < 3; ++r)
            #pragma unroll
            for (int col = 0; col < 3; ++col)
                covp[r * 3 + col] = L[r][0] * L[col][0]
                                  + L[r][1] * L[col][1]
                                  + L[r][2] * L[col][2];

        float* harp = out + (size_t)12 * N_PTS + (size_t)i * 3;
        harp[0] = f2[it].z;
        harp[1] = f2[it].w;
        harp[2] = f3[it].x;

        out[(size_t)15 * N_PTS + i] = 1.f / (1.f + expf(-(f3[it].y - 4.f)));
    }

    // block reduction -> 2 double atomics
    #pragma unroll
    for (int off = 32; off > 0; off >>= 1) {
        s  += __shfl_down(s, off, 64);
        ss += __shfl_down(ss, off, 64);
    }
    __shared__ float sh_s[4], sh_ss[4];
    const int lane = threadIdx.x & 63;
    const int wid  = threadIdx.x >> 6;
    if (lane == 0) { sh_s[wid] = s; sh_ss[wid] = ss; }
    __syncthreads();
    if (threadIdx.x == 0) {
        float ts = 0.f, tss = 0.f;
        for (int w = 0; w < 4; ++w) { ts += sh_s[w]; tss += sh_ss[w]; }
        atomicAdd(&acc[0], (double)ts);
        atomicAdd(&acc[1], (double)tss);
    }
}

// ---------------------------------------------------------------------------
// Pass B: streaming finalize of means (~75 MB total traffic).
// means = (dm_raw - mean) * inv_std * dm_scale + voxel_center
// ---------------------------------------------------------------------------
__global__ __launch_bounds__(256)
void finalize_means_kernel(const int*    __restrict__ coords,
                           const float*  __restrict__ cam,
                           const float*  __restrict__ far_p,
                           const int*    __restrict__ vs_p,
                           const double* __restrict__ acc,
                           float*        __restrict__ out) {
    const double n      = 3.0 * (double)N_PTS;
    const double sum    = acc[0];
    const double sumsq  = acc[1];
    const float  mean   = (float)(sum / n);
    const float  inv_std= (float)(1.0 / sqrt((sumsq - sum * sum / n) / (n - 1.0)));

    const float far_s = far_p[0];
    const float vs    = (float)vs_p[0];
    const float a     = inv_std * (2.f * far_s / vs / 6.f);
    const float off_c = -far_s + far_s / vs;
    const float cam_t[3] = { cam[0], cam[1], cam[2] };

    const int base = blockIdx.x * PA_THREADS + threadIdx.x;
    #pragma unroll
    for (int it = 0; it < PA_ITERS; ++it) {
        const int i = base + it * PA_STRIDE;
        const size_t b = (size_t)i * 3;
        const int cc[3] = { coords[b + 0], coords[b + 1], coords[b + 2] };
        #pragma unroll
        for (int k = 0; k < 3; ++k) {
            const float vc = (float)cc[k] / vs * 2.f * far_s + off_c + cam_t[k];
            const float dm = out[b + k];
            out[b + k] = (dm - mean) * a + vc;
        }
    }
}

// ---------------------------------------------------------------------------
// Fallback path (workspace too small for the transposed table).
// ---------------------------------------------------------------------------
__global__ void reduce_kernel_o(const int* __restrict__ coords,
                                const float* __restrict__ table,
                                double* __restrict__ acc) {
    float s = 0.f, ss = 0.f;
    const int stride = gridDim.x * blockDim.x;
    for (int i = blockIdx.x * blockDim.x + threadIdx.x; i < N_PTS; i += stride) {
        const unsigned idx = hash_idx(coords[i*3], coords[i*3+1], coords[i*3+2]);
        float g0 = table[idx];
        float g1 = table[T_HASH + idx];
        float g2 = table[2 * T_HASH + idx];
        s  += g0 + g1 + g2;
        ss += g0 * g0 + g1 * g1 + g2 * g2;
    }
    #pragma unroll
    for (int off = 32; off > 0; off >>= 1) {
        s  += __shfl_down(s, off, 64);
        ss += __shfl_down(ss, off, 64);
    }
    __shared__ float sh_s[4], sh_ss[4];
    const int lane = threadIdx.x & 63;
    const int wid  = threadIdx.x >> 6;
    if (lane == 0) { sh_s[wid] = s; sh_ss[wid] = ss; }
    __syncthreads();
    if (threadIdx.x == 0) {
        float ts = 0.f, tss = 0.f;
        for (int w = 0; w < 4; ++w) { ts += sh_s[w]; tss += sh_ss[w]; }
        atomicAdd(&acc[0], (double)ts);
        atomicAdd(&acc[1], (double)tss);
    }
}

__global__ void main_kernel_o(const int* __restrict__ coords,
                              const float* __restrict__ tab,
                              const float* __restrict__ cam,
                              const float* __restrict__ far_p,
                              const int* __restrict__ vs_p,
                              const double* __restrict__ acc,
                              float* __restrict__ out) {
    const int i = blockIdx.x * blockDim.x + threadIdx.x;
    if (i >= N_PTS) return;

    const float far_s = far_p[0];
    const float vs    = (float)vs_p[0];

    const double n      = 3.0 * (double)N_PTS;
    const double sum    = acc[0];
    const double sumsq  = acc[1];
    const float mean    = (float)(sum / n);
    const float inv_std = (float)(1.0 / sqrt((sumsq - sum * sum / n) / (n - 1.0)));

    const int cx = coords[i * 3 + 0];
    const int cy = coords[i * 3 + 1];
    const int cz = coords[i * 3 + 2];
    const unsigned idx = hash_idx(cx, cy, cz);

    float g[14];
    #pragma unroll
    for (int j = 0; j < 14; ++j)
        g[j] = tab[(size_t)j * T_HASH + idx];

    const float two_far_over_vs = 2.f * far_s / vs;
    const float dm_scale = two_far_over_vs / 6.f;
    const float c_f[3] = { (float)cx, (float)cy, (float)cz };
    #pragma unroll
    for (int k = 0; k < 3; ++k) {
        const float vc = c_f[k] / vs * 2.f * far_s - far_s + cam[k] + far_s / vs;
        out[(size_t)i * 3 + k] = (g[k] - mean) * inv_std * dm_scale + vc;
    }

    float qr = g[3], qx = g[4], qy = g[5], qz = g[6];
    const float qinv = 1.f / sqrtf(qr * qr + qx * qx + qy * qy + qz * qz);
    qr *= qinv; qx *= qinv; qy *= qinv; qz *= qinv;

    float R[3][3];
    R[0][0] = 1.f - 2.f * (qy * qy + qz * qz);
    R[0][1] = 2.f * (qx * qy - qr * qz);
    R[0][2] = 2.f * (qx * qz + qr * qy);
    R[1][0] = 2.f * (qx * qy + qr * qz);
    R[1][1] = 1.f - 2.f * (qx * qx + qz * qz);
    R[1][2] = 2.f * (qy * qz - qr * qx);
    R[2][0] = 2.f * (qx * qz - qr * qy);
    R[2][1] = 2.f * (qy * qz + qr * qx);
    R[2][2] = 1.f - 2.f * (qx * qx + qy * qy);

    float sc[3];
    #pragma unroll
    for (int k = 0; k < 3; ++k)
        sc[k] = two_far_over_vs / (1.f + expf(-g[7 + k]));

    float* covp = out + (size_t)3 * N_PTS + (size_t)i * 9;
    #pragma unroll
    for (int r = 0; r < 3; ++r) {
        #pragma unroll
        for (int c = 0; c < 3; ++c) {
            float a = 0.f;
            #pragma unroll
            for (int j = 0; j < 3; ++j)
                a += (R[r][j] * sc[j]) * (R[c][j] * sc[j]);
            covp[r * 3 + c] = a;
        }
    }

    float* harp = out + (size_t)12 * N_PTS + (size_t)i * 3;
    #pragma unroll
    for (int k = 0; k < 3; ++k)
        harp[k] = g[10 + k];

    out[(size_t)15 * N_PTS + i] = 1.f / (1.f + expf(-(g[13] - 4.f)));
}

extern "C" void kernel_launch(void* const* d_in, const int* in_sizes, int n_in,
                              void* d_out, int out_size, void* d_ws, size_t ws_size,
                              hipStream_t stream) {
    const int*   coords = (const int*)d_in[0];
    const float* table  = (const float*)d_in[1];
    const float* cam    = (const float*)d_in[2];
    const float* far_p  = (const float*)d_in[3];
    const int*   vs_p   = (const int*)d_in[4];
    float*       out    = (float*)d_out;

    double* acc = (double*)d_ws;
    float*  tt  = (float*)((char*)d_ws + 256);

    const size_t need = 256 + (size_t)T_HASH * ENTRY_STRIDE * sizeof(float);

    if (ws_size >= need) {
        // acc zeroed by transpose_kernel block 0 (stream order guarantees
        // completion before fused_main_kernel's atomics).
        transpose_kernel<<<T_HASH / 256, 256, 0, stream>>>(table, tt, acc);
        fused_main_kernel<<<PA_BLOCKS, PA_THREADS, 0, stream>>>(coords, tt, far_p,
                                                                vs_p, out, acc);
        finalize_means_kernel<<<PA_BLOCKS, PA_THREADS, 0, stream>>>(coords, cam,
                                                                    far_p, vs_p,
                                                                    acc, out);
    } else {
        hipMemsetAsync(d_ws, 0, 2 * sizeof(double), stream);
        const int threads = 256;
        const int blocks  = (N_PTS + threads - 1) / threads;
        reduce_kernel_o<<<2048, 256, 0, stream>>>(coords, table, acc);
        main_kernel_o<<<blocks, threads, 0, stream>>>(coords, table, cam,
                                                      far_p, vs_p, acc, out);
    }
}